// Round 6
// baseline (299.412 us; speedup 1.0000x reference)
//
#include <hip/hip_runtime.h>
#include <stdint.h>

#define HIDDEN 1024
#define HEADS 16
#define HEAD_DIM 64
#define BATCH 4
#define SEQ 2048
#define ROWS (BATCH * SEQ) /* 8192 */
#define MB 1048576ull

typedef float f32x4 __attribute__((ext_vector_type(4)));
typedef short bf16x8 __attribute__((ext_vector_type(8))); // 8 bf16 = 4 VGPRs

__device__ __forceinline__ uint16_t f32_to_bf16_rne(float f) {
    uint32_t u = __float_as_uint(f);
    uint32_t r = u + 0x7FFFu + ((u >> 16) & 1u);
    return (uint16_t)(r >> 16);
}
__device__ __forceinline__ float bf16_to_f32(uint16_t u) {
    return __uint_as_float(((uint32_t)u) << 16);
}

// ---------------------------------------------------------------------------
// Kernel 0: Xq fp32 -> bf16 rows (for final_gemm A operand). 4096 blocks.
// ---------------------------------------------------------------------------
__global__ __launch_bounds__(256) void cvtq_kernel(const float* __restrict__ Xq,
                                                   uint16_t* __restrict__ Xqb) {
    size_t e = ((size_t)blockIdx.x * 256 + threadIdx.x) * 8;
    float4 f0 = *(const float4*)(Xq + e);
    float4 f1 = *(const float4*)(Xq + e + 4);
    uint4 pk;
    pk.x = (uint32_t)f32_to_bf16_rne(f0.x) | ((uint32_t)f32_to_bf16_rne(f0.y) << 16);
    pk.y = (uint32_t)f32_to_bf16_rne(f0.z) | ((uint32_t)f32_to_bf16_rne(f0.w) << 16);
    pk.z = (uint32_t)f32_to_bf16_rne(f1.x) | ((uint32_t)f32_to_bf16_rne(f1.y) << 16);
    pk.w = (uint32_t)f32_to_bf16_rne(f1.z) | ((uint32_t)f32_to_bf16_rne(f1.w) << 16);
    *(uint4*)(Xqb + e) = pk;
}

// ---------------------------------------------------------------------------
// Kernel 1: transposing convert. Xk/Xv [8192 s][1024 p] fp32 -> XT [1024 p][8192 s] bf16.
// grid (128 sc, 16 pc, 2 z), block 256, 64x64 tile via LDS.
// ---------------------------------------------------------------------------
__global__ __launch_bounds__(256) void cvtT_kernel(const float* __restrict__ Xk,
                                                   const float* __restrict__ Xv,
                                                   uint16_t* __restrict__ XkT,
                                                   uint16_t* __restrict__ XvT) {
    const float* X = blockIdx.z == 0 ? Xk : Xv;
    uint16_t* XT = blockIdx.z == 0 ? XkT : XvT;
    const int s0 = blockIdx.x * 64, p0 = blockIdx.y * 64;
    const int tid = threadIdx.x;
    const int w = tid >> 6, l = tid & 63;

    __shared__ uint16_t tile[64 * 65];
    for (int it = 0; it < 16; ++it) {
        int s = it * 4 + w;
        tile[s * 65 + l] = f32_to_bf16_rne(X[(size_t)(s0 + s) * HIDDEN + p0 + l]);
    }
    __syncthreads();
    for (int pass = 0; pass < 2; ++pass) {
        int p = (tid >> 3) + 32 * pass;
        int c = tid & 7;
        bf16x8 v;
        for (int e = 0; e < 8; ++e) v[e] = (short)tile[(c * 8 + e) * 65 + p];
        *(bf16x8*)(XT + (size_t)(p0 + p) * ROWS + s0 + c * 8) = v;
    }
}

// ---------------------------------------------------------------------------
// Kernel 2: W[K][N] fp32 -> Wt[N][K] bf16, z in {Wk, Wv}
// ---------------------------------------------------------------------------
__global__ __launch_bounds__(256) void wt_kernel(const float* __restrict__ Wk,
                                                 const float* __restrict__ Wv,
                                                 uint16_t* __restrict__ Wt) {
    const float* W = blockIdx.z == 0 ? Wk : Wv;
    uint16_t* out = Wt + (size_t)blockIdx.z * HIDDEN * HIDDEN;
    __shared__ float tile[64][65];
    int k0 = blockIdx.x * 64, n0 = blockIdx.y * 64;
    int r = threadIdx.x >> 6, c = threadIdx.x & 63;
    for (int it = 0; it < 16; ++it) {
        int rr = r + 4 * it;
        tile[rr][c] = W[(size_t)(k0 + rr) * HIDDEN + n0 + c];
    }
    __syncthreads();
    for (int it = 0; it < 16; ++it) {
        int rr = r + 4 * it;
        out[(size_t)(n0 + rr) * HIDDEN + k0 + c] = f32_to_bf16_rne(tile[c][rr]);
    }
}

// ---------------------------------------------------------------------------
// Kernel 3: generic bf16 GEMM  C[m][n] = sum_k A[m][k]*B[n][k]  (bf16 out).
//   m97 structure, 128x128 tile, BK=64, XOR-swizzled LDS, async staging.
//   Per-batch pointer advance via aBS/bBS/cBS (element strides).
// ---------------------------------------------------------------------------
__global__ __launch_bounds__(256) void gemm_bt(const uint16_t* __restrict__ A, int lda, long long aBS,
                                               const uint16_t* __restrict__ B, int ldb, long long bBS,
                                               uint16_t* __restrict__ C, int ldc, long long cBS,
                                               int klen) {
    const int bz = blockIdx.z;
    A += (size_t)aBS * bz;
    B += (size_t)bBS * bz;
    C += (size_t)cBS * bz;

    __shared__ uint16_t lds[16384];

    const int tid = threadIdx.x;
    const int lane = tid & 63;
    const int w = tid >> 6;
    const int wm = (w >> 1) * 64;
    const int wn = (w & 1) * 64;
    const int m_lane = lane & 15;
    const int kq = lane >> 4;
    const int m0 = blockIdx.x * 128;
    const int n0 = blockIdx.y * 128;

    f32x4 acc[4][4] = {};

    for (int kb = 0; kb < klen; kb += 64) {
        for (int t = 0; t < 4; ++t) {
            int gbase = (w * 4 + t) * 64;
            int g = gbase + lane;
            int r = g >> 3;
            int c = (g & 7) ^ (r & 7);
            const uint16_t* srcA = A + (size_t)(m0 + r) * lda + kb + c * 8;
            __builtin_amdgcn_global_load_lds(
                (const __attribute__((address_space(1))) uint32_t*)srcA,
                (__attribute__((address_space(3))) uint32_t*)(&lds[gbase * 8]),
                16, 0, 0);
            const uint16_t* srcB = B + (size_t)(n0 + r) * ldb + kb + c * 8;
            __builtin_amdgcn_global_load_lds(
                (const __attribute__((address_space(1))) uint32_t*)srcB,
                (__attribute__((address_space(3))) uint32_t*)(&lds[8192 + gbase * 8]),
                16, 0, 0);
        }
        __syncthreads();
        for (int ks = 0; ks < 2; ++ks) {
            int cbase = ks * 4 + kq;
            bf16x8 af[4], bfr[4];
            for (int i = 0; i < 4; ++i) {
                int r = wm + i * 16 + m_lane;
                int p = cbase ^ (r & 7);
                af[i] = *(const bf16x8*)(&lds[r * 64 + p * 8]);
            }
            for (int j = 0; j < 4; ++j) {
                int nr = wn + j * 16 + m_lane;
                int p = cbase ^ (nr & 7);
                bfr[j] = *(const bf16x8*)(&lds[8192 + nr * 64 + p * 8]);
            }
            for (int i = 0; i < 4; ++i)
                for (int j = 0; j < 4; ++j)
                    acc[i][j] = __builtin_amdgcn_mfma_f32_16x16x32_bf16(
                        af[i], bfr[j], acc[i][j], 0, 0, 0);
        }
        __syncthreads();
    }

    for (int j = 0; j < 4; ++j) {
        int col = n0 + wn + j * 16 + m_lane;
        for (int i = 0; i < 4; ++i) {
            int rbase = m0 + wm + i * 16 + kq * 4;
            for (int rg = 0; rg < 4; ++rg)
                C[(size_t)(rbase + rg) * ldc + col] = f32_to_bf16_rne(acc[i][j][rg]);
        }
    }
}

// ---------------------------------------------------------------------------
// Kernel 4: column sums  ck[z][b][p] = sum_{s in batch b} X_z[s][p], from XT.
//   One wave per (z,b,p). grid 2048 blocks x 256.
// ---------------------------------------------------------------------------
__global__ __launch_bounds__(256) void colsum_kernel(const uint16_t* __restrict__ XkT,
                                                     const uint16_t* __restrict__ XvT,
                                                     float* __restrict__ ck) {
    const int w = threadIdx.x >> 6, l = threadIdx.x & 63;
    const int gw = blockIdx.x * 4 + w;
    const int z = gw >> 12;
    const int rem = gw & 4095;
    const int b = rem >> 10, p = rem & 1023;
    const uint16_t* XT = z == 0 ? XkT : XvT;
    const uint16_t* row = XT + (size_t)p * ROWS + b * SEQ;

    float s = 0.f;
    for (int it = 0; it < 4; ++it) {
        bf16x8 v = *(const bf16x8*)(row + it * 512 + l * 8);
        for (int e = 0; e < 8; ++e) s += bf16_to_f32((uint16_t)v[e]);
    }
    for (int off = 32; off; off >>= 1) s += __shfl_down(s, off);
    if (l == 0) ck[z * 4096 + b * 1024 + p] = s;
}

// ---------------------------------------------------------------------------
// Kernel 5: uv[z][b][i] = sum_p Wt[z][i][p] * ck[z][b][p].
//   One wave per (z,i), all 4 b. grid 512 x 256.
// ---------------------------------------------------------------------------
__global__ __launch_bounds__(256) void uv_kernel(const uint16_t* __restrict__ Wt,
                                                 const float* __restrict__ ck,
                                                 float* __restrict__ uv) {
    const int w = threadIdx.x >> 6, l = threadIdx.x & 63;
    const int gw = blockIdx.x * 4 + w;
    const int z = gw >> 10;
    const int i = gw & 1023;
    const uint16_t* wr = Wt + (size_t)z * HIDDEN * HIDDEN + (size_t)i * HIDDEN + l * 16;
    bf16x8 w0 = *(const bf16x8*)wr;
    bf16x8 w1 = *(const bf16x8*)(wr + 8);
    const float* cb = ck + z * 4096;

    float acc[4] = {};
    for (int e = 0; e < 8; ++e) {
        float we = bf16_to_f32((uint16_t)w0[e]);
        float wf = bf16_to_f32((uint16_t)w1[e]);
        int pa = l * 16 + e, pb = l * 16 + 8 + e;
        for (int b = 0; b < 4; ++b)
            acc[b] += we * cb[b * 1024 + pa] + wf * cb[b * 1024 + pb];
    }
    for (int b = 0; b < 4; ++b)
        for (int off = 32; off; off >>= 1) acc[b] += __shfl_down(acc[b], off);
    if (l == 0)
        for (int b = 0; b < 4; ++b) uv[z * 4096 + b * 1024 + i] = acc[b];
}

// ---------------------------------------------------------------------------
// Kernel 6: M[bh][i][j] = 0.125*( sum_n T_b[h64+i][n]*Wtv[h64+j][n]
//                                 + u[b][gi]*bv[gj] + bk[gi]*(v[b][gj]+2048*bv[gj]) )
//   64x64x1024 MFMA per (b,h). grid 64 x 256 (4 waves, wave w = m-band w*16).
// ---------------------------------------------------------------------------
__global__ __launch_bounds__(256) void mfold_kernel(const uint16_t* __restrict__ T,
                                                    const uint16_t* __restrict__ Wt,
                                                    const float* __restrict__ Bk,
                                                    const float* __restrict__ Bv,
                                                    const float* __restrict__ uv,
                                                    float* __restrict__ M) {
    const int b = blockIdx.x >> 4, h = blockIdx.x & 15;
    const uint16_t* A = T + (size_t)b * MB + (size_t)h * 64 * HIDDEN;       // 64 rows
    const uint16_t* B = Wt + (size_t)HIDDEN * HIDDEN + (size_t)h * 64 * HIDDEN; // Wtv rows

    __shared__ uint16_t lds[8192]; // A [0,4096), B [4096,8192)

    const int tid = threadIdx.x;
    const int lane = tid & 63;
    const int w = tid >> 6;
    const int m_lane = lane & 15;
    const int kq = lane >> 4;

    f32x4 acc[4] = {};

    for (int kb = 0; kb < HIDDEN; kb += 64) {
        for (int t = 0; t < 2; ++t) {
            int gbase = (w * 2 + t) * 64;
            int g = gbase + lane;
            int r = g >> 3;
            int c = (g & 7) ^ (r & 7);
            const uint16_t* srcA = A + (size_t)r * HIDDEN + kb + c * 8;
            __builtin_amdgcn_global_load_lds(
                (const __attribute__((address_space(1))) uint32_t*)srcA,
                (__attribute__((address_space(3))) uint32_t*)(&lds[gbase * 8]),
                16, 0, 0);
            const uint16_t* srcB = B + (size_t)r * HIDDEN + kb + c * 8;
            __builtin_amdgcn_global_load_lds(
                (const __attribute__((address_space(1))) uint32_t*)srcB,
                (__attribute__((address_space(3))) uint32_t*)(&lds[4096 + gbase * 8]),
                16, 0, 0);
        }
        __syncthreads();
        for (int ks = 0; ks < 2; ++ks) {
            int cbase = ks * 4 + kq;
            int r = w * 16 + m_lane;
            int p = cbase ^ (r & 7);
            bf16x8 af = *(const bf16x8*)(&lds[r * 64 + p * 8]);
            for (int j = 0; j < 4; ++j) {
                int nr = j * 16 + m_lane;
                int pb = cbase ^ (nr & 7);
                bf16x8 bfr = *(const bf16x8*)(&lds[4096 + nr * 64 + pb * 8]);
                acc[j] = __builtin_amdgcn_mfma_f32_16x16x32_bf16(af, bfr, acc[j], 0, 0, 0);
            }
        }
        __syncthreads();
    }

    const float* u_ = uv + b * 1024;
    const float* v_ = uv + 4096 + b * 1024;
    float* Mout = M + ((size_t)(b * 16 + h)) * 4096;
    for (int j = 0; j < 4; ++j) {
        int col = j * 16 + m_lane;
        int gj = h * 64 + col;
        float bvj = Bv[gj];
        float vj = v_[gj] + 2048.f * bvj;
        for (int rg = 0; rg < 4; ++rg) {
            int i = w * 16 + kq * 4 + rg;
            int gi = h * 64 + i;
            float val = 0.125f * (acc[j][rg] + u_[gi] * bvj + Bk[gi] * vj);
            Mout[i * 64 + col] = val;
        }
    }
}

// ---------------------------------------------------------------------------
// Kernel 7: fold M into weights — per batch.
//   W't[b][n=h64+j][k=r] = sum_i Wq[r][h64+i] * M[b16+h][i][j]   (bf16)
//   b'[b][n]             = sum_i bq[h64+i]    * M[b16+h][i][j]   (fp32)
// ---------------------------------------------------------------------------
__global__ __launch_bounds__(256) void wprime_kernel(const float* __restrict__ Wq,
                                                     const float* __restrict__ bq,
                                                     const float* __restrict__ M,
                                                     uint16_t* __restrict__ Wpt,
                                                     float* __restrict__ bp) {
    const int h = blockIdx.x;
    const int r0 = blockIdx.y * 64;
    const int b = blockIdx.z;
    const int tid = threadIdx.x;

    __shared__ float Mh[64][65];
    __shared__ float Wl[64][65];
    for (int it = 0; it < 16; ++it) {
        int e = it * 256 + tid;
        int a = e >> 6, c = e & 63;
        Mh[a][c] = M[((size_t)(b * 16 + h)) * 4096 + e];
        Wl[a][c] = Wq[(size_t)(r0 + a) * HIDDEN + h * 64 + c];
    }
    __syncthreads();

    const int r = tid & 63;
    const int jbase = tid >> 6; // 0..3
    float acc[16] = {};
    for (int i = 0; i < 64; ++i) {
        float wv = Wl[r][i];
        for (int jj = 0; jj < 16; ++jj)
            acc[jj] += wv * Mh[i][jbase + 4 * jj];
    }
    uint16_t* Wb = Wpt + (size_t)b * HIDDEN * HIDDEN;
    for (int jj = 0; jj < 16; ++jj) {
        int n = h * 64 + jbase + 4 * jj;
        Wb[(size_t)n * HIDDEN + r0 + r] = f32_to_bf16_rne(acc[jj]);
    }

    if (blockIdx.y == 0 && tid < 64) {
        int j = tid;
        float s = 0.f;
        for (int i = 0; i < 64; ++i) s += bq[h * 64 + i] * Mh[i][j];
        bp[b * HIDDEN + h * 64 + j] = s;
    }
}

// ---------------------------------------------------------------------------
// Kernel 8: out = Xq @ W'_b^T + b'_b   (fp32 output to d_out)
// ---------------------------------------------------------------------------
__global__ __launch_bounds__(256) void final_gemm(const uint16_t* __restrict__ Xq,
                                                  const uint16_t* __restrict__ Wpt,
                                                  const float* __restrict__ bp,
                                                  float* __restrict__ out) {
    __shared__ uint16_t lds[16384];

    const int tid = threadIdx.x;
    const int lane = tid & 63;
    const int w = tid >> 6;
    const int wm = (w >> 1) * 64;
    const int wn = (w & 1) * 64;
    const int m_lane = lane & 15;
    const int kq = lane >> 4;
    const int m0 = blockIdx.x * 128;
    const int n0 = blockIdx.y * 128;
    const int batch = m0 >> 11;
    const uint16_t* W = Wpt + (size_t)batch * HIDDEN * HIDDEN;
    const float* bias = bp + batch * HIDDEN;

    f32x4 acc[4][4] = {};

    for (int kb = 0; kb < HIDDEN; kb += 64) {
        for (int t = 0; t < 4; ++t) {
            int gbase = (w * 4 + t) * 64;
            int g = gbase + lane;
            int r = g >> 3;
            int c = (g & 7) ^ (r & 7);
            const uint16_t* srcA = Xq + (size_t)(m0 + r) * HIDDEN + kb + c * 8;
            __builtin_amdgcn_global_load_lds(
                (const __attribute__((address_space(1))) uint32_t*)srcA,
                (__attribute__((address_space(3))) uint32_t*)(&lds[gbase * 8]),
                16, 0, 0);
            const uint16_t* srcB = W + (size_t)(n0 + r) * HIDDEN + kb + c * 8;
            __builtin_amdgcn_global_load_lds(
                (const __attribute__((address_space(1))) uint32_t*)srcB,
                (__attribute__((address_space(3))) uint32_t*)(&lds[8192 + gbase * 8]),
                16, 0, 0);
        }
        __syncthreads();
        for (int ks = 0; ks < 2; ++ks) {
            int cbase = ks * 4 + kq;
            bf16x8 af[4], bfr[4];
            for (int i = 0; i < 4; ++i) {
                int r = wm + i * 16 + m_lane;
                int p = cbase ^ (r & 7);
                af[i] = *(const bf16x8*)(&lds[r * 64 + p * 8]);
            }
            for (int j = 0; j < 4; ++j) {
                int nr = wn + j * 16 + m_lane;
                int p = cbase ^ (nr & 7);
                bfr[j] = *(const bf16x8*)(&lds[8192 + nr * 64 + p * 8]);
            }
            for (int i = 0; i < 4; ++i)
                for (int j = 0; j < 4; ++j)
                    acc[i][j] = __builtin_amdgcn_mfma_f32_16x16x32_bf16(
                        af[i], bfr[j], acc[i][j], 0, 0, 0);
        }
        __syncthreads();
    }

    for (int j = 0; j < 4; ++j) {
        int col = n0 + wn + j * 16 + m_lane;
        float bj = bias[col];
        for (int i = 0; i < 4; ++i) {
            int rbase = m0 + wm + i * 16 + kq * 4;
            for (int rg = 0; rg < 4; ++rg)
                out[(size_t)(rbase + rg) * HIDDEN + col] = acc[i][j][rg] + bj;
        }
    }
}

// ---------------------------------------------------------------------------
extern "C" void kernel_launch(void* const* d_in, const int* in_sizes, int n_in,
                              void* d_out, int out_size, void* d_ws, size_t ws_size,
                              hipStream_t stream) {
    const float* Xq = (const float*)d_in[0];
    const float* Xk = (const float*)d_in[1];
    const float* Xv = (const float*)d_in[2];
    const float* Wq = (const float*)d_in[3];
    const float* Bq = (const float*)d_in[4];
    const float* Wk = (const float*)d_in[5];
    const float* Bk = (const float*)d_in[6];
    const float* Wv = (const float*)d_in[7];
    const float* Bv = (const float*)d_in[8];
    float* out = (float*)d_out;

    char* ws = (char*)d_ws;
    uint16_t* Xqb = (uint16_t*)(ws);            // 16 MB  @ 0
    uint16_t* XvT = (uint16_t*)(ws + 16 * MB);  // 16 MB  @ 16M
    uint16_t* XkT = (uint16_t*)(ws + 32 * MB);  // 16 MB  @ 32M
    uint16_t* Wt  = (uint16_t*)(ws + 48 * MB);  //  4 MB  @ 48M  (Wtk, Wtv)
    uint16_t* H   = (uint16_t*)(ws + 52 * MB);  //  8 MB  @ 52M
    float*    M   = (float*)   (ws + 60 * MB);  //  1 MB  @ 60M
    float*    ck  = (float*)   (ws + 61 * MB);  // 32 KB
    float*    uvb = (float*)   (ws + 61 * MB + 32768);  // 32 KB
    float*    bp  = (float*)   (ws + 61 * MB + 65536);  // 16 KB  (total ~61.1 MB)
    // aliases (safe by stream order):
    uint16_t* T   = XvT;   // 8 MB, written by t_gemm after all XvT readers
    uint16_t* Wpt = XkT;   // 8 MB, written by wprime after all XkT readers

    cvtq_kernel<<<dim3(4096), 256, 0, stream>>>(Xq, Xqb);
    cvtT_kernel<<<dim3(128, 16, 2), 256, 0, stream>>>(Xk, Xv, XkT, XvT);
    wt_kernel<<<dim3(16, 16, 2), 256, 0, stream>>>(Wk, Wv, Wt);

    // H_b[n][p] = sum_s XvT[n][bS+s] * XkT[p][bS+s]
    gemm_bt<<<dim3(8, 8, 4), 256, 0, stream>>>(XvT, ROWS, 2048ll, XkT, ROWS, 2048ll,
                                               H, HIDDEN, (long long)(MB / 1), 2048);
    colsum_kernel<<<dim3(2048), 256, 0, stream>>>(XkT, XvT, ck);
    uv_kernel<<<dim3(512), 256, 0, stream>>>(Wt, ck, uvb);

    // T_b[i'][n] = sum_p Wtk[i'][p] * H_b[n][p]
    gemm_bt<<<dim3(8, 8, 4), 256, 0, stream>>>(Wt, HIDDEN, 0ll, H, HIDDEN, (long long)MB,
                                               T, HIDDEN, (long long)MB, 1024);
    mfold_kernel<<<dim3(64), 256, 0, stream>>>(T, Wt, Bk, Bv, uvb, M);
    wprime_kernel<<<dim3(16, 16, 4), 256, 0, stream>>>(Wq, Bq, M, Wpt, bp);
    final_gemm<<<dim3(64, 8), 256, 0, stream>>>(Xqb, Wpt, bp, out);
}